// Round 2
// baseline (2778.054 us; speedup 1.0000x reference)
//
#include <hip/hip_runtime.h>
#include <hip/hip_bf16.h>
#include <math.h>

#define BB   32
#define CCH  256
#define TT   64
#define VV   50
#define TVV  3200            // T*V tokens per batch
#define XB   819200          // 256*3200 floats per batch of x / out

__device__ __forceinline__ unsigned short f2bf(float f) {
  __hip_bfloat16 h = __float2bfloat16(f);
  union { __hip_bfloat16 h; unsigned short u; } cv; cv.h = h; return cv.u;
}
__device__ __forceinline__ float bf2f(unsigned short u) {
  return __uint_as_float(((unsigned)u) << 16);
}

// ---------------- K1: LN1 stats per token (over 256 channels of x)
// x layout (B,C,T,V); token m_local in chunk -> b = b0 + m/3200, tv = m%3200
__global__ __launch_bounds__(256)
void ln1_stats_kernel(const float* __restrict__ x, int b0,
                      float* __restrict__ mean, float* __restrict__ rstd) {
  int m0 = blockIdx.x * 64;                   // local token base (same b for all 64)
  int b = b0 + m0 / TVV, tv0 = m0 % TVV;
  int lane = threadIdx.x & 63, grp = threadIdx.x >> 6;
  const float* xb = x + (size_t)b * XB + tv0 + lane;
  float s = 0.f, ss = 0.f;
  for (int k = grp; k < CCH; k += 4) {
    float v = xb[(size_t)k * TVV];
    s += v; ss += v * v;
  }
  __shared__ float rs_[4][64], rss_[4][64];
  rs_[grp][lane] = s; rss_[grp][lane] = ss;
  __syncthreads();
  if (threadIdx.x < 64) {
    s  = rs_[0][lane] + rs_[1][lane] + rs_[2][lane] + rs_[3][lane];
    ss = rss_[0][lane] + rss_[1][lane] + rss_[2][lane] + rss_[3][lane];
    float m = s * (1.f / CCH);
    float var = ss * (1.f / CCH) - m * m;
    mean[m0 + lane] = m;
    rstd[m0 + lane] = rsqrtf(var + 1e-5f);
  }
}

// ---------------- K2: map GEMM with fused LN1.
// A^T(k=c, m) = LN(x[b][c][tv]); B=map_w(256,512); out f=(512,Mc) +bias
__global__ __launch_bounds__(256)
void gemm_map_kernel(const float* __restrict__ x, int b0, int Mc,
                     const float* __restrict__ mean, const float* __restrict__ rstd,
                     const float* __restrict__ n1w, const float* __restrict__ n1b,
                     const float* __restrict__ Bw, const float* __restrict__ bias,
                     float* __restrict__ f) {
  __shared__ float sA[16][64];
  __shared__ float sB[16][64];
  int m0 = blockIdx.x * 64, n0 = blockIdx.y * 64;
  int b = b0 + m0 / TVV, tv0 = m0 % TVV;
  int tid = threadIdx.x;
  int tx = tid & 15, ty = tid >> 4;
  int lk = tid >> 4, lm = (tid & 15) << 2;
  const float* xb = x + (size_t)b * XB + tv0;
  float4 mu = *(const float4*)(mean + m0 + lm);
  float4 rs = *(const float4*)(rstd + m0 + lm);
  float acc[4][4] = {};
  for (int k0 = 0; k0 < 256; k0 += 16) {
    float4 a = *(const float4*)(xb + (size_t)(k0 + lk) * TVV + lm);
    float wk = n1w[k0 + lk], bk = n1b[k0 + lk];
    float4 tt;
    tt.x = (a.x - mu.x) * rs.x * wk + bk;
    tt.y = (a.y - mu.y) * rs.y * wk + bk;
    tt.z = (a.z - mu.z) * rs.z * wk + bk;
    tt.w = (a.w - mu.w) * rs.w * wk + bk;
    *(float4*)&sA[lk][lm] = tt;
    *(float4*)&sB[lk][lm] = *(const float4*)(Bw + (size_t)(k0 + lk) * 512 + n0 + lm);
    __syncthreads();
#pragma unroll
    for (int kk = 0; kk < 16; ++kk) {
      float a4[4], bb[4];
      *(float4*)a4 = *(const float4*)&sA[kk][tx << 2];
      *(float4*)bb = *(const float4*)&sB[kk][ty << 2];
#pragma unroll
      for (int i = 0; i < 4; ++i)
#pragma unroll
        for (int j = 0; j < 4; ++j) acc[i][j] += a4[i] * bb[j];
    }
    __syncthreads();
  }
#pragma unroll
  for (int j = 0; j < 4; ++j) {
    int n = n0 + (ty << 2) + j;
    float bz = bias[n];
    float* dst = f + (size_t)n * Mc + m0 + (tx << 2);
#pragma unroll
    for (int i = 0; i < 4; ++i) dst[i] = acc[i][j] + bz;
  }
}

// ---------------- K3: grouped graph conv over V. f ch 0..63 -> ycat ch 0..63
__global__ __launch_bounds__(256)
void gconv_kernel(const float* __restrict__ f, int Mc, const float* __restrict__ gw,
                  float* __restrict__ ycat) {
  int bc = blockIdx.x / TT, t = blockIdx.x % TT;   // bc = batch-in-chunk
  __shared__ float sf[64][51];
  int tid = threadIdx.x;
  const float* fb = f + (size_t)bc * TVV + t * VV;
  for (int idx = tid; idx < 64 * 50; idx += 256) {
    int oc = idx / 50, u = idx % 50;
    sf[oc][u] = fb[(size_t)oc * Mc + u];
  }
  __syncthreads();
  float* yb = ycat + (size_t)bc * TVV + t * VV;
  for (int idx = tid; idx < 64 * 50; idx += 256) {
    int oc = idx / 50, vv = idx % 50;
    int g = oc >> 3;
    const float* gr = gw + ((size_t)g * 50 + vv) * 50;
    float s = 0.f;
    for (int u = 0; u < 50; ++u) s += sf[oc][u] * gr[u];
    yb[(size_t)oc * Mc + vv] = s;
  }
}

// ---------------- K4: grouped temporal conv (k=7, pad 3). f ch 64..127 -> ycat 64..127
__global__ __launch_bounds__(256)
void tconv_kernel(const float* __restrict__ f, int Mc, const float* __restrict__ tw,
                  const float* __restrict__ tb, float* __restrict__ ycat) {
  int bc = blockIdx.x >> 6, oc = blockIdx.x & 63;
  int g = oc >> 3;
  __shared__ float sw[56];
  int tid = threadIdx.x;
  if (tid < 56) sw[tid] = tw[oc * 56 + tid];        // (64,8,7,1) row-major
  __syncthreads();
  float bias = tb[oc];
  const float* fb = f + (size_t)(64 + g * 8) * Mc + (size_t)bc * TVV;
  float* yb = ycat + (size_t)(64 + oc) * Mc + (size_t)bc * TVV;
  for (int idx = tid; idx < TT * VV; idx += 256) {
    int t = idx / VV, vv = idx % VV;
    float s = bias;
#pragma unroll
    for (int ic = 0; ic < 8; ++ic) {
      const float* fc = fb + (size_t)ic * Mc + vv;
#pragma unroll
      for (int kt = 0; kt < 7; ++kt) {
        int ts = t + kt - 3;
        if (ts >= 0 && ts < TT) s += fc[ts * VV] * sw[ic * 7 + kt];
      }
    }
    yb[idx] = s;
  }
}

// ---------------- K5: windowed hyperbolic linear attention (4 modes)
// f channels 128+mode*96 .. +96  ->  ycat channels 128+mode*32 .. +32
__global__ __launch_bounds__(256)
void attn_kernel(const float* __restrict__ f, int Mc, float* __restrict__ ycat) {
  int mode = blockIdx.z;            // 0..3 (= reference modes 1..4)
  int bc   = blockIdx.y;
  int wt = blockIdx.x / 5, wv = blockIdx.x % 5;
  __shared__ float parts[80][97];
  __shared__ float kvbuf[256];
  __shared__ float obuf[80][33];
  __shared__ float scl[80];
  int tid = threadIdx.x;

  const float* fbase = f + (size_t)(128 + mode * 96) * Mc + (size_t)bc * TVV;
  for (int idx = tid; idx < 96 * 80; idx += 256) {
    int ch = idx / 80, n = idx % 80;
    int lt = n / 10, lv = n % 10;
    int t = (mode < 2) ? (wt * 8 + lt) : (lt * 8 + wt);
    int v = ((mode & 1) == 0) ? (wv * 10 + lv) : (lv * 5 + wv);
    parts[n][ch] = fbase[(size_t)ch * Mc + t * VV + v];
  }
  __syncthreads();
  // euc -> poincare: scale token vector by tanh(n)/n
  if (tid < 80) {
    float s = 0.f;
    for (int ch = 0; ch < 96; ++ch) { float val = parts[tid][ch]; s += val * val; }
    float nrm = fmaxf(sqrtf(s), 1e-10f);
    float sc = tanhf(nrm) / nrm;
    for (int ch = 0; ch < 96; ++ch) parts[tid][ch] *= sc;
  }
  __syncthreads();
  // kv[h][d][e] = sum_n k[h,n,d] * v[h,n,e]   (256 threads = 4*8*8)
  {
    int h = tid >> 6, dd = (tid >> 3) & 7, e = tid & 7;
    float s = 0.f;
    for (int n = 0; n < 80; ++n)
      s += parts[n][32 + h * 8 + dd] * parts[n][64 + h * 8 + e];
    kvbuf[tid] = s;
  }
  __syncthreads();
  // softmax over e for each (h,d)
  if (tid < 32) {
    int h = tid >> 3, dd = tid & 7;
    float* r = &kvbuf[h * 64 + dd * 8];
    float mx = r[0];
    for (int e = 1; e < 8; ++e) mx = fmaxf(mx, r[e]);
    float ex[8]; float sm = 0.f;
    for (int e = 0; e < 8; ++e) { ex[e] = expf(r[e] - mx); sm += ex[e]; }
    float inv = 1.f / sm;
    for (int e = 0; e < 8; ++e) r[e] = ex[e] * inv;
  }
  __syncthreads();
  // attn[n][h*8+m] = 0.5 * sum_i q[n][h*8+i] * kv[h][m][i]
  for (int idx = tid; idx < 80 * 32; idx += 256) {
    int n = idx >> 5, cc = idx & 31;
    int h = cc >> 3, m_ = cc & 7;
    float s = 0.f;
#pragma unroll
    for (int i = 0; i < 8; ++i)
      s += parts[n][h * 8 + i] * kvbuf[h * 64 + m_ * 8 + i];
    obuf[n][cc] = s * 0.5f;
  }
  __syncthreads();
  // poincare -> euc: scale by -atanh(n)/n, n clipped [1e-10, 1-1e-5]
  if (tid < 80) {
    float s = 0.f;
    for (int cc = 0; cc < 32; ++cc) { float val = obuf[tid][cc]; s += val * val; }
    float nn = sqrtf(s);
    nn = fminf(fmaxf(nn, 1e-10f), 1.f - 1e-5f);
    scl[tid] = -atanhf(nn) / nn;
  }
  __syncthreads();
  float* yb = ycat + (size_t)(128 + mode * 32) * Mc + (size_t)bc * TVV;
  for (int idx = tid; idx < 80 * 32; idx += 256) {
    int n = idx >> 5, cc = idx & 31;
    int lt = n / 10, lv = n % 10;
    int t = (mode < 2) ? (wt * 8 + lt) : (lt * 8 + wt);
    int v = ((mode & 1) == 0) ? (wv * 10 + lv) : (lv * 5 + wv);
    yb[(size_t)cc * Mc + t * VV + v] = obuf[n][cc] * scl[n];
  }
}

// ---------------- K6: proj GEMM + skip. A^T=ycat(256,Mc), B=proj_w(256,256)
// writes out1 directly into d_out at final (B,C,T,V) layout
__global__ __launch_bounds__(256)
void gemm_proj_kernel(const float* __restrict__ At, int b0, int Mc,
                      const float* __restrict__ Bw, const float* __restrict__ bias,
                      const float* __restrict__ x, float* __restrict__ out) {
  __shared__ float sA[16][64];
  __shared__ float sB[16][64];
  int m0 = blockIdx.x * 64, n0 = blockIdx.y * 64;
  int b = b0 + m0 / TVV, tv0 = m0 % TVV;
  int tid = threadIdx.x;
  int tx = tid & 15, ty = tid >> 4;
  int lk = tid >> 4, lm = (tid & 15) << 2;
  float acc[4][4] = {};
  for (int k0 = 0; k0 < 256; k0 += 16) {
    *(float4*)&sA[lk][lm] = *(const float4*)(At + (size_t)(k0 + lk) * Mc + m0 + lm);
    *(float4*)&sB[lk][lm] = *(const float4*)(Bw + (size_t)(k0 + lk) * 256 + n0 + lm);
    __syncthreads();
#pragma unroll
    for (int kk = 0; kk < 16; ++kk) {
      float a4[4], bb[4];
      *(float4*)a4 = *(const float4*)&sA[kk][tx << 2];
      *(float4*)bb = *(const float4*)&sB[kk][ty << 2];
#pragma unroll
      for (int i = 0; i < 4; ++i)
#pragma unroll
        for (int j = 0; j < 4; ++j) acc[i][j] += a4[i] * bb[j];
    }
    __syncthreads();
  }
#pragma unroll
  for (int j = 0; j < 4; ++j) {
    int n = n0 + (ty << 2) + j;
    float bz = bias[n];
    const float* xp = x   + (size_t)b * XB + (size_t)n * TVV + tv0 + (tx << 2);
    float* dst      = out + (size_t)b * XB + (size_t)n * TVV + tv0 + (tx << 2);
#pragma unroll
    for (int i = 0; i < 4; ++i) dst[i] = acc[i][j] + bz + xp[i];
  }
}

// ---------------- K7: LN2 stats per token (over 256 channels of out)
__global__ __launch_bounds__(256)
void ln2_stats_kernel(const float* __restrict__ out, int b0,
                      float* __restrict__ mean, float* __restrict__ rstd) {
  int m0 = blockIdx.x * 64;
  int b = b0 + m0 / TVV, tv0 = m0 % TVV;
  int lane = threadIdx.x & 63, grp = threadIdx.x >> 6;
  const float* ob = out + (size_t)b * XB + tv0 + lane;
  float s = 0.f, ss = 0.f;
  for (int k = grp; k < CCH; k += 4) {
    float v = ob[(size_t)k * TVV];
    s += v; ss += v * v;
  }
  __shared__ float rs_[4][64], rss_[4][64];
  rs_[grp][lane] = s; rss_[grp][lane] = ss;
  __syncthreads();
  if (threadIdx.x < 64) {
    s  = rs_[0][lane] + rs_[1][lane] + rs_[2][lane] + rs_[3][lane];
    ss = rss_[0][lane] + rss_[1][lane] + rss_[2][lane] + rss_[3][lane];
    float m = s * (1.f / CCH);
    float var = ss * (1.f / CCH) - m * m;
    mean[m0 + lane] = m;
    rstd[m0 + lane] = rsqrtf(var + 1e-5f);
  }
}

// ---------------- K8: MLP1 GEMM, fused LN2 + exact GELU, hmid bf16 (1024, Mc)
__global__ __launch_bounds__(256)
void gemm_mlp1_kernel(const float* __restrict__ out, int b0, int Mc,
                      const float* __restrict__ Bw, const float* __restrict__ bias,
                      const float* __restrict__ mean, const float* __restrict__ rstd,
                      const float* __restrict__ n2w, const float* __restrict__ n2b,
                      unsigned short* __restrict__ hmid) {
  __shared__ float sA[16][64];
  __shared__ float sB[16][64];
  int m0 = blockIdx.x * 64, n0 = blockIdx.y * 64;
  int b = b0 + m0 / TVV, tv0 = m0 % TVV;
  int tid = threadIdx.x;
  int tx = tid & 15, ty = tid >> 4;
  int lk = tid >> 4, lm = (tid & 15) << 2;
  const float* ob = out + (size_t)b * XB + tv0;
  float4 mu = *(const float4*)(mean + m0 + lm);
  float4 rs = *(const float4*)(rstd + m0 + lm);
  float acc[4][4] = {};
  for (int k0 = 0; k0 < 256; k0 += 16) {
    float4 a = *(const float4*)(ob + (size_t)(k0 + lk) * TVV + lm);
    float wk = n2w[k0 + lk], bk = n2b[k0 + lk];
    float4 tt;
    tt.x = (a.x - mu.x) * rs.x * wk + bk;
    tt.y = (a.y - mu.y) * rs.y * wk + bk;
    tt.z = (a.z - mu.z) * rs.z * wk + bk;
    tt.w = (a.w - mu.w) * rs.w * wk + bk;
    *(float4*)&sA[lk][lm] = tt;
    *(float4*)&sB[lk][lm] = *(const float4*)(Bw + (size_t)(k0 + lk) * 1024 + n0 + lm);
    __syncthreads();
#pragma unroll
    for (int kk = 0; kk < 16; ++kk) {
      float a4[4], bb[4];
      *(float4*)a4 = *(const float4*)&sA[kk][tx << 2];
      *(float4*)bb = *(const float4*)&sB[kk][ty << 2];
#pragma unroll
      for (int i = 0; i < 4; ++i)
#pragma unroll
        for (int j = 0; j < 4; ++j) acc[i][j] += a4[i] * bb[j];
    }
    __syncthreads();
  }
#pragma unroll
  for (int j = 0; j < 4; ++j) {
    int n = n0 + (ty << 2) + j;
    float bz = bias[n];
    ushort4 pk;
    float h;
    h = acc[0][j] + bz; pk.x = f2bf(0.5f * h * (1.f + erff(h * 0.70710678118f)));
    h = acc[1][j] + bz; pk.y = f2bf(0.5f * h * (1.f + erff(h * 0.70710678118f)));
    h = acc[2][j] + bz; pk.z = f2bf(0.5f * h * (1.f + erff(h * 0.70710678118f)));
    h = acc[3][j] + bz; pk.w = f2bf(0.5f * h * (1.f + erff(h * 0.70710678118f)));
    *(ushort4*)(hmid + (size_t)n * Mc + m0 + (tx << 2)) = pk;
  }
}

// ---------------- K9: MLP2 GEMM + bias + residual (in-place on d_out)
__global__ __launch_bounds__(256)
void gemm_mlp2_kernel(const unsigned short* __restrict__ hmid, int b0, int Mc,
                      const float* __restrict__ Bw, const float* __restrict__ bias,
                      float* __restrict__ out) {
  __shared__ float sA[16][64];
  __shared__ float sB[16][64];
  int m0 = blockIdx.x * 64, n0 = blockIdx.y * 64;
  int b = b0 + m0 / TVV, tv0 = m0 % TVV;
  int tid = threadIdx.x;
  int tx = tid & 15, ty = tid >> 4;
  int lk = tid >> 4, lm = (tid & 15) << 2;
  float acc[4][4] = {};
  for (int k0 = 0; k0 < 1024; k0 += 16) {
    ushort4 u = *(const ushort4*)(hmid + (size_t)(k0 + lk) * Mc + m0 + lm);
    sA[lk][lm + 0] = bf2f(u.x);
    sA[lk][lm + 1] = bf2f(u.y);
    sA[lk][lm + 2] = bf2f(u.z);
    sA[lk][lm + 3] = bf2f(u.w);
    *(float4*)&sB[lk][lm] = *(const float4*)(Bw + (size_t)(k0 + lk) * 256 + n0 + lm);
    __syncthreads();
#pragma unroll
    for (int kk = 0; kk < 16; ++kk) {
      float a4[4], bb[4];
      *(float4*)a4 = *(const float4*)&sA[kk][tx << 2];
      *(float4*)bb = *(const float4*)&sB[kk][ty << 2];
#pragma unroll
      for (int i = 0; i < 4; ++i)
#pragma unroll
        for (int j = 0; j < 4; ++j) acc[i][j] += a4[i] * bb[j];
    }
    __syncthreads();
  }
#pragma unroll
  for (int j = 0; j < 4; ++j) {
    int n = n0 + (ty << 2) + j;
    float bz = bias[n];
    float* dst = out + (size_t)b * XB + (size_t)n * TVV + tv0 + (tx << 2);
#pragma unroll
    for (int i = 0; i < 4; ++i) dst[i] = dst[i] + acc[i][j] + bz;
  }
}

extern "C" void kernel_launch(void* const* d_in, const int* in_sizes, int n_in,
                              void* d_out, int out_size, void* d_ws, size_t ws_size,
                              hipStream_t stream) {
  const float* x       = (const float*)d_in[0];
  const float* n1w     = (const float*)d_in[1];
  const float* n1b     = (const float*)d_in[2];
  const float* map_w   = (const float*)d_in[3];
  const float* map_b   = (const float*)d_in[4];
  const float* gconv   = (const float*)d_in[5];
  const float* tconv_w = (const float*)d_in[6];
  const float* tconv_b = (const float*)d_in[7];
  const float* proj_w  = (const float*)d_in[8];
  const float* proj_b  = (const float*)d_in[9];
  const float* n2w     = (const float*)d_in[10];
  const float* n2b     = (const float*)d_in[11];
  const float* w1      = (const float*)d_in[12];
  const float* b1      = (const float*)d_in[13];
  const float* w2      = (const float*)d_in[14];
  const float* b2      = (const float*)d_in[15];
  float* out = (float*)d_out;

  // Per-token workspace bytes: f fp32 512ch (2048 B) [overlaid with hmid bf16
  // 1024ch (2048 B)] + ycat fp32 256ch (1024 B) + 4 stats floats (16 B) = 3088 B.
  // All ops are per-batch independent -> chunk over b if ws is small.
  int CH = 32;                                   // batches per chunk
  while (CH > 1 && (size_t)3088 * CH * TVV > ws_size) CH >>= 1;
  if ((size_t)3088 * CH * TVV > ws_size) return; // <10 MB ws: cannot run safely
  const int Mc = CH * TVV;                       // tokens per chunk
  const int nchunks = BB / CH;

  char* ws = (char*)d_ws;
  float* f            = (float*)ws;                               // (512, Mc) fp32
  unsigned short* hmid = (unsigned short*)ws;                     // (1024, Mc) bf16 (overlay)
  float* ycat         = (float*)(ws + (size_t)2048 * Mc);         // (256, Mc) fp32
  float* stats        = (float*)(ws + (size_t)3072 * Mc);
  float* mean1 = stats, *rstd1 = stats + Mc, *mean2 = stats + 2 * Mc, *rstd2 = stats + 3 * Mc;

  for (int c = 0; c < nchunks; ++c) {
    int b0 = c * CH;
    ln1_stats_kernel<<<dim3(Mc / 64), 256, 0, stream>>>(x, b0, mean1, rstd1);
    gemm_map_kernel<<<dim3(Mc / 64, 8), 256, 0, stream>>>(x, b0, Mc, mean1, rstd1,
                                                          n1w, n1b, map_w, map_b, f);
    gconv_kernel<<<dim3(CH * TT), 256, 0, stream>>>(f, Mc, gconv, ycat);
    tconv_kernel<<<dim3(CH * TT), 256, 0, stream>>>(f, Mc, tconv_w, tconv_b, ycat);
    attn_kernel<<<dim3(40, CH, 4), 256, 0, stream>>>(f, Mc, ycat);
    gemm_proj_kernel<<<dim3(Mc / 64, 4), 256, 0, stream>>>(ycat, b0, Mc, proj_w, proj_b, x, out);
    ln2_stats_kernel<<<dim3(Mc / 64), 256, 0, stream>>>(out, b0, mean2, rstd2);
    gemm_mlp1_kernel<<<dim3(Mc / 64, 16), 256, 0, stream>>>(out, b0, Mc, w1, b1,
                                                            mean2, rstd2, n2w, n2b, hmid);
    gemm_mlp2_kernel<<<dim3(Mc / 64, 4), 256, 0, stream>>>(hmid, b0, Mc, w2, b2, out);
  }
}

// Round 3
// 1068.418 us; speedup vs baseline: 2.6002x; 2.6002x over previous
//
#include <hip/hip_runtime.h>
#include <hip/hip_bf16.h>
#include <math.h>

#define BB  32
#define TT  64
#define VV  50
#define TVV 3200

typedef __attribute__((ext_vector_type(8))) short s8v;   // 8 x bf16 (4 VGPR)
typedef __attribute__((ext_vector_type(4))) float f4v;   // MFMA accumulator

__device__ __forceinline__ unsigned short f2bf(float f) {
  __hip_bfloat16 h = __float2bfloat16(f);
  union { __hip_bfloat16 h; unsigned short u; } cv; cv.h = h; return cv.u;
}

#define LPITCH 40   // LDS row pitch in bf16 elems (32 data + 8 pad -> conflict-friendly)

// ---------------- shared MFMA GEMM core: C(128x128) = A(M,K) x B(N,K)^T, bf16 in fp32 acc
template<int K>
__device__ __forceinline__ void gemm_core(const unsigned short* __restrict__ A,
                                          const unsigned short* __restrict__ B,
                                          int m0, int n0,
                                          unsigned short* sA, unsigned short* sB,
                                          f4v (&acc)[4][4]) {
  const int tid  = threadIdx.x;
  const int lane = tid & 63;
  const int wave = tid >> 6;
  const int wr = wave >> 1, wc = wave & 1;
  const int q = lane >> 4, l15 = lane & 15;
  const int row0 = tid >> 2;            // staging: element e=i*256+tid -> row e>>2
  const int kq0  = (tid & 3) << 3;      // k-offset within 32 (units of 8 bf16 = 16B)
  for (int k0 = 0; k0 < K; k0 += 32) {
#pragma unroll
    for (int i = 0; i < 2; ++i) {
      int row = row0 + i * 64;
      s8v av = *(const s8v*)(A + (size_t)(m0 + row) * K + k0 + kq0);
      s8v bv = *(const s8v*)(B + (size_t)(n0 + row) * K + k0 + kq0);
      *(s8v*)(sA + row * LPITCH + kq0) = av;
      *(s8v*)(sB + row * LPITCH + kq0) = bv;
    }
    __syncthreads();
    s8v af[4], bfr[4];
#pragma unroll
    for (int i = 0; i < 4; ++i) {
      af[i]  = *(const s8v*)(sA + (wr * 64 + i * 16 + l15) * LPITCH + q * 8);
      bfr[i] = *(const s8v*)(sB + (wc * 64 + i * 16 + l15) * LPITCH + q * 8);
    }
#pragma unroll
    for (int mi = 0; mi < 4; ++mi)
#pragma unroll
      for (int ni = 0; ni < 4; ++ni)
        acc[mi][ni] = __builtin_amdgcn_mfma_f32_16x16x32_bf16(af[mi], bfr[ni], acc[mi][ni], 0, 0, 0);
    __syncthreads();
  }
}

// ---------------- weight prep: src fp32 (K,N) -> dst bf16 (N,K)
__global__ __launch_bounds__(256)
void k_wprep(const float* __restrict__ src, unsigned short* __restrict__ dst, int K, int N) {
  int idx = blockIdx.x * 256 + threadIdx.x;
  if (idx >= N * K) return;
  int n = idx / K, k = idx - n * K;
  dst[idx] = f2bf(src[(size_t)k * N + n]);
}

// ---------------- x (B,C,T,V) channel-major -> xtok fp32 (Mc,256) token-major
__global__ __launch_bounds__(256)
void k_xpose(const float* __restrict__ x, int b0, float* __restrict__ xtok) {
  __shared__ float sx[64][65];
  int m0 = blockIdx.x * 64;             // chunk-local token base (within one batch: 3200=50*64)
  int c0 = blockIdx.y * 64;
  int b = b0 + m0 / TVV, tv0 = m0 % TVV;
  int tid = threadIdx.x;
  int tvi = tid & 63, ci = tid >> 6;
  const float* xb = x + ((size_t)b * 256 + c0) * TVV + tv0;
#pragma unroll
  for (int j = 0; j < 16; ++j) {
    int cc = ci + j * 4;
    sx[cc][tvi] = xb[(size_t)cc * TVV + tvi];
  }
  __syncthreads();
  int cj = tid & 63, rj = tid >> 6;
#pragma unroll
  for (int j = 0; j < 16; ++j) {
    int tv = rj + j * 4;
    xtok[(size_t)(m0 + tv) * 256 + c0 + cj] = sx[cj][tv];
  }
}

// ---------------- fused LayerNorm (over 256) fp32 src -> bf16 dst, token-major
__global__ __launch_bounds__(256)
void k_ln(const float* __restrict__ src, const float* __restrict__ w, const float* __restrict__ b,
          unsigned short* __restrict__ dst) {
  int tid = threadIdx.x;
  int tk = tid >> 2, p = tid & 3;
  size_t m = (size_t)blockIdx.x * 64 + tk;
  const float4* row = (const float4*)(src + m * 256 + p * 64);
  float4 r[16];
  float s = 0.f, ss = 0.f;
#pragma unroll
  for (int j = 0; j < 16; ++j) {
    r[j] = row[j];
    s  += r[j].x + r[j].y + r[j].z + r[j].w;
    ss += r[j].x*r[j].x + r[j].y*r[j].y + r[j].z*r[j].z + r[j].w*r[j].w;
  }
  __shared__ float sb1[256], sb2[256];
  sb1[tid] = s; sb2[tid] = ss;
  __syncthreads();
  int base = tk << 2;
  s  = sb1[base] + sb1[base+1] + sb1[base+2] + sb1[base+3];
  ss = sb2[base] + sb2[base+1] + sb2[base+2] + sb2[base+3];
  float mu = s * (1.f / 256.f);
  float rstd = rsqrtf(ss * (1.f / 256.f) - mu * mu + 1e-5f);
  ushort4* drow = (ushort4*)(dst + m * 256 + p * 64);
#pragma unroll
  for (int j = 0; j < 16; ++j) {
    int c = p * 64 + j * 4;
    ushort4 o;
    o.x = f2bf((r[j].x - mu) * rstd * w[c]     + b[c]);
    o.y = f2bf((r[j].y - mu) * rstd * w[c + 1] + b[c + 1]);
    o.z = f2bf((r[j].z - mu) * rstd * w[c + 2] + b[c + 2]);
    o.w = f2bf((r[j].w - mu) * rstd * w[c + 3] + b[c + 3]);
    drow[j] = o;
  }
}

// ---------------- map GEMM: xln(Mc,256)bf16 x wmapT(512,256) -> f fp32 (Mc,512)
__global__ __launch_bounds__(256)
void k_gemm_map(const unsigned short* __restrict__ xln, const unsigned short* __restrict__ wT,
                const float* __restrict__ bias, float* __restrict__ f) {
  __shared__ __align__(16) unsigned short sm[2 * 128 * LPITCH];
  int m0 = blockIdx.x * 128, n0 = blockIdx.y * 128;
  f4v acc[4][4];
#pragma unroll
  for (int i = 0; i < 4; ++i)
#pragma unroll
    for (int j = 0; j < 4; ++j) acc[i][j] = (f4v){0.f, 0.f, 0.f, 0.f};
  gemm_core<256>(xln, wT, m0, n0, sm, sm + 128 * LPITCH, acc);
  const int tid = threadIdx.x, lane = tid & 63, wave = tid >> 6;
  const int wr = wave >> 1, wc = wave & 1, q = lane >> 4, l15 = lane & 15;
#pragma unroll
  for (int ni = 0; ni < 4; ++ni) {
    int n = n0 + wc * 64 + ni * 16 + l15;
    float bz = bias[n];
#pragma unroll
    for (int mi = 0; mi < 4; ++mi) {
      int m = m0 + wr * 64 + mi * 16 + q * 4;
#pragma unroll
      for (int rr = 0; rr < 4; ++rr)
        f[(size_t)(m + rr) * 512 + n] = acc[mi][ni][rr] + bz;
    }
  }
}

// ---------------- proj GEMM: ycat(Mc,256)bf16 x wprojT(256,256) + bias + skip (in-place xtok->out1)
__global__ __launch_bounds__(256)
void k_gemm_proj(const unsigned short* __restrict__ ycat, const unsigned short* __restrict__ wT,
                 const float* __restrict__ bias, float* __restrict__ out1) {
  __shared__ __align__(16) unsigned short sm[2 * 128 * LPITCH];
  int m0 = blockIdx.x * 128, n0 = blockIdx.y * 128;
  f4v acc[4][4];
#pragma unroll
  for (int i = 0; i < 4; ++i)
#pragma unroll
    for (int j = 0; j < 4; ++j) acc[i][j] = (f4v){0.f, 0.f, 0.f, 0.f};
  gemm_core<256>(ycat, wT, m0, n0, sm, sm + 128 * LPITCH, acc);
  const int tid = threadIdx.x, lane = tid & 63, wave = tid >> 6;
  const int wr = wave >> 1, wc = wave & 1, q = lane >> 4, l15 = lane & 15;
#pragma unroll
  for (int ni = 0; ni < 4; ++ni) {
    int n = n0 + wc * 64 + ni * 16 + l15;
    float bz = bias[n];
#pragma unroll
    for (int mi = 0; mi < 4; ++mi) {
      int m = m0 + wr * 64 + mi * 16 + q * 4;
#pragma unroll
      for (int rr = 0; rr < 4; ++rr) {
        size_t idx = (size_t)(m + rr) * 256 + n;
        out1[idx] = out1[idx] + acc[mi][ni][rr] + bz;   // xtok (skip) lives here
      }
    }
  }
}

// ---------------- mlp1 GEMM: xln2(Mc,256)bf16 x w1T(1024,256) + bias -> GELU -> hmid bf16 (Mc,1024)
__global__ __launch_bounds__(256)
void k_gemm_mlp1(const unsigned short* __restrict__ xln2, const unsigned short* __restrict__ wT,
                 const float* __restrict__ bias, unsigned short* __restrict__ hmid) {
  __shared__ __align__(16) unsigned short sm[2 * 128 * LPITCH];
  int m0 = blockIdx.x * 128, n0 = blockIdx.y * 128;
  f4v acc[4][4];
#pragma unroll
  for (int i = 0; i < 4; ++i)
#pragma unroll
    for (int j = 0; j < 4; ++j) acc[i][j] = (f4v){0.f, 0.f, 0.f, 0.f};
  gemm_core<256>(xln2, wT, m0, n0, sm, sm + 128 * LPITCH, acc);
  const int tid = threadIdx.x, lane = tid & 63, wave = tid >> 6;
  const int wr = wave >> 1, wc = wave & 1, q = lane >> 4, l15 = lane & 15;
#pragma unroll
  for (int ni = 0; ni < 4; ++ni) {
    int n = n0 + wc * 64 + ni * 16 + l15;
    float bz = bias[n];
#pragma unroll
    for (int mi = 0; mi < 4; ++mi) {
      int m = m0 + wr * 64 + mi * 16 + q * 4;
#pragma unroll
      for (int rr = 0; rr < 4; ++rr) {
        float h = acc[mi][ni][rr] + bz;
        float g = 0.5f * h * (1.f + erff(h * 0.70710678118654752f));
        hmid[(size_t)(m + rr) * 1024 + n] = f2bf(g);
      }
    }
  }
}

// ---------------- mlp2 GEMM: hmid(Mc,1024)bf16 x w2T(256,1024) + bias + out1 -> d_out (B,C,T,V)
__global__ __launch_bounds__(256)
void k_gemm_mlp2(const unsigned short* __restrict__ hmid, const unsigned short* __restrict__ wT,
                 const float* __restrict__ bias, const float* __restrict__ out1,
                 float* __restrict__ out, int b0) {
  __shared__ __align__(16) unsigned short sm[2 * 128 * LPITCH];   // 20480 B; reused for transpose
  int m0 = blockIdx.x * 128, n0 = blockIdx.y * 128;
  f4v acc[4][4];
#pragma unroll
  for (int i = 0; i < 4; ++i)
#pragma unroll
    for (int j = 0; j < 4; ++j) acc[i][j] = (f4v){0.f, 0.f, 0.f, 0.f};
  gemm_core<1024>(hmid, wT, m0, n0, sm, sm + 128 * LPITCH, acc);
  const int tid = threadIdx.x, lane = tid & 63, wave = tid >> 6;
  const int wr = wave >> 1, wc = wave & 1, q = lane >> 4, l15 = lane & 15;
  float* twv = (float*)sm + wave * 16 * 65;     // 4 waves * 1040 floats = 16640 B <= 20480
  int mbase = m0 + wr * 64;
  int bglob = b0 + mbase / TVV;
  int tvb = mbase % TVV;
  for (int ni = 0; ni < 4; ++ni) {
    int n = n0 + wc * 64 + ni * 16 + l15;
    float bz = bias[n];
#pragma unroll
    for (int mi = 0; mi < 4; ++mi) {
      int ml = mi * 16 + q * 4;
#pragma unroll
      for (int rr = 0; rr < 4; ++rr) {
        int m = mbase + ml + rr;
        twv[l15 * 65 + ml + rr] = acc[mi][ni][rr] + bz + out1[(size_t)m * 256 + n];
      }
    }
    __syncthreads();
#pragma unroll
    for (int np = 0; np < 16; ++np) {
      int n2 = n0 + wc * 64 + ni * 16 + np;
      out[((size_t)bglob * 256 + n2) * TVV + tvb + lane] = twv[np * 65 + lane];
    }
    __syncthreads();
  }
}

// ---------------- grouped graph conv over V: f ch 0..63 -> ycat ch 0..63 (bf16)
__global__ __launch_bounds__(256)
void k_gconv(const float* __restrict__ f, const float* __restrict__ gw,
             unsigned short* __restrict__ ycat) {
  __shared__ float sf[50][64];
  int bc = blockIdx.x >> 6, t = blockIdx.x & 63;
  int tid = threadIdx.x;
  size_t tok0 = (size_t)bc * TVV + t * 50;
  for (int idx = tid; idx < 3200; idx += 256) {
    int u = idx >> 6, oc = idx & 63;
    sf[u][oc] = f[(tok0 + u) * 512 + oc];
  }
  __syncthreads();
  for (int idx = tid; idx < 3200; idx += 256) {
    int v = idx >> 6, oc = idx & 63;
    const float* gr = gw + ((size_t)(oc >> 3) * 50 + v) * 50;
    float s = 0.f;
#pragma unroll 10
    for (int u = 0; u < 50; ++u) s += sf[u][oc] * gr[u];
    ycat[(tok0 + v) * 256 + oc] = f2bf(s);
  }
}

// ---------------- grouped temporal conv k=7 pad3: f ch 64..127 -> ycat ch 64..127 (bf16)
__global__ __launch_bounds__(256)
void k_tconv(const float* __restrict__ f, const float* __restrict__ tw,
             const float* __restrict__ tb, unsigned short* __restrict__ ycat) {
  __shared__ float sw[64 * 57];
  int bc = blockIdx.x >> 6, t = blockIdx.x & 63;
  int tid = threadIdx.x;
  for (int idx = tid; idx < 64 * 56; idx += 256) {
    int oc = idx / 56, k = idx - oc * 56;
    sw[oc * 57 + k] = tw[idx];                  // (64,8,7,1) row-major
  }
  __syncthreads();
  size_t base = (size_t)bc * TVV;
  for (int idx = tid; idx < 3200; idx += 256) {
    int v = idx >> 6, oc = idx & 63;
    int g = oc >> 3;
    float s = tb[oc];
#pragma unroll
    for (int kt = 0; kt < 7; ++kt) {
      int ts = t + kt - 3;
      if (ts < 0 || ts >= 64) continue;
      const float* fr = f + (base + ts * 50 + v) * 512 + 64 + g * 8;
      const float* wr_ = sw + oc * 57 + kt;
#pragma unroll
      for (int ic = 0; ic < 8; ++ic) s += fr[ic] * wr_[ic * 7];
    }
    ycat[(base + t * 50 + v) * 256 + 64 + oc] = f2bf(s);
  }
}

// ---------------- windowed hyperbolic linear attention, 4 modes -> ycat ch 128..255 (bf16)
__global__ __launch_bounds__(256)
void k_attn(const float* __restrict__ f, unsigned short* __restrict__ ycat) {
  int mode = blockIdx.z, bc = blockIdx.y;
  int wt = blockIdx.x / 5, wv = blockIdx.x % 5;
  __shared__ float parts[80][97];
  __shared__ float kvb[256];
  __shared__ float obuf[80][33];
  __shared__ float scl[80];
  int tid = threadIdx.x;
  size_t base = (size_t)bc * TVV;
  int ch0 = 128 + mode * 96;
  for (int idx = tid; idx < 80 * 96; idx += 256) {
    int n = idx / 96, ch = idx - n * 96;
    int lt = n / 10, lv = n - lt * 10;
    int t = (mode < 2) ? (wt * 8 + lt) : (lt * 8 + wt);
    int v = ((mode & 1) == 0) ? (wv * 10 + lv) : (lv * 5 + wv);
    parts[n][ch] = f[(base + t * 50 + v) * 512 + ch0 + ch];
  }
  __syncthreads();
  if (tid < 80) {                                   // euc -> poincare
    float s = 0.f;
    for (int ch = 0; ch < 96; ++ch) { float val = parts[tid][ch]; s += val * val; }
    float nrm = fmaxf(sqrtf(s), 1e-10f);
    float sc = tanhf(nrm) / nrm;
    for (int ch = 0; ch < 96; ++ch) parts[tid][ch] *= sc;
  }
  __syncthreads();
  {                                                 // kv[h][d][e]
    int h = tid >> 6, dd = (tid >> 3) & 7, e = tid & 7;
    float s = 0.f;
    for (int n = 0; n < 80; ++n)
      s += parts[n][32 + h * 8 + dd] * parts[n][64 + h * 8 + e];
    kvb[tid] = s;
  }
  __syncthreads();
  if (tid < 32) {                                   // softmax over e
    int h = tid >> 3, dd = tid & 7;
    float* r = &kvb[h * 64 + dd * 8];
    float mx = r[0];
    for (int e = 1; e < 8; ++e) mx = fmaxf(mx, r[e]);
    float ex[8]; float sm2 = 0.f;
    for (int e = 0; e < 8; ++e) { ex[e] = expf(r[e] - mx); sm2 += ex[e]; }
    float inv = 1.f / sm2;
    for (int e = 0; e < 8; ++e) r[e] = ex[e] * inv;
  }
  __syncthreads();
  for (int idx = tid; idx < 80 * 32; idx += 256) {  // attn = 0.5 * q . kv
    int n = idx >> 5, cc = idx & 31;
    int h = cc >> 3, m_ = cc & 7;
    float s = 0.f;
#pragma unroll
    for (int i = 0; i < 8; ++i)
      s += parts[n][h * 8 + i] * kvb[h * 64 + m_ * 8 + i];
    obuf[n][cc] = s * 0.5f;
  }
  __syncthreads();
  if (tid < 80) {                                   // poincare -> euc
    float s = 0.f;
    for (int cc = 0; cc < 32; ++cc) { float val = obuf[tid][cc]; s += val * val; }
    float nn = sqrtf(s);
    nn = fminf(fmaxf(nn, 1e-10f), 1.f - 1e-5f);
    scl[tid] = -atanhf(nn) / nn;
  }
  __syncthreads();
  for (int idx = tid; idx < 80 * 32; idx += 256) {
    int n = idx >> 5, cc = idx & 31;
    int lt = n / 10, lv = n - lt * 10;
    int t = (mode < 2) ? (wt * 8 + lt) : (lt * 8 + wt);
    int v = ((mode & 1) == 0) ? (wv * 10 + lv) : (lv * 5 + wv);
    ycat[(base + t * 50 + v) * 256 + 128 + mode * 32 + cc] = f2bf(obuf[n][cc] * scl[n]);
  }
}

extern "C" void kernel_launch(void* const* d_in, const int* in_sizes, int n_in,
                              void* d_out, int out_size, void* d_ws, size_t ws_size,
                              hipStream_t stream) {
  const float* x       = (const float*)d_in[0];
  const float* n1w     = (const float*)d_in[1];
  const float* n1b     = (const float*)d_in[2];
  const float* map_w   = (const float*)d_in[3];
  const float* map_b   = (const float*)d_in[4];
  const float* gconv   = (const float*)d_in[5];
  const float* tconv_w = (const float*)d_in[6];
  const float* tconv_b = (const float*)d_in[7];
  const float* proj_w  = (const float*)d_in[8];
  const float* proj_b  = (const float*)d_in[9];
  const float* n2w     = (const float*)d_in[10];
  const float* n2b     = (const float*)d_in[11];
  const float* w1      = (const float*)d_in[12];
  const float* b1      = (const float*)d_in[13];
  const float* w2      = (const float*)d_in[14];
  const float* b2      = (const float*)d_in[15];
  float* out = (float*)d_out;

  // per-token ws: xtok/out1 fp32 (1024 B) | f fp32 512ch (2048 B, overlaid hmid bf16 1024ch)
  //             | xln bf16 (512 B) | ycat bf16 (512 B)  = 4096 B/token; + 1.44 MB bf16 weights
  const size_t WB = (size_t)(512 * 256 + 256 * 256 + 1024 * 256 + 256 * 1024) * 2;
  int CH = 32;
  while (CH > 1 && (size_t)CH * TVV * 4096 + WB > ws_size) CH >>= 1;
  if ((size_t)CH * TVV * 4096 + WB > ws_size) return;
  const int Mc = CH * TVV;
  const int nch = BB / CH;

  char* ws = (char*)d_ws;
  float* xtok            = (float*)ws;                                 // (Mc,256) -> out1 in-place
  float* f               = (float*)(ws + (size_t)Mc * 1024);           // (Mc,512)
  unsigned short* hmid   = (unsigned short*)f;                         // (Mc,1024) overlay
  unsigned short* xln    = (unsigned short*)(ws + (size_t)Mc * 3072);  // (Mc,256)
  unsigned short* ycat   = (unsigned short*)(ws + (size_t)Mc * 3584);  // (Mc,256)
  unsigned short* wmapT  = (unsigned short*)(ws + (size_t)Mc * 4096);  // (512,256)
  unsigned short* wprojT = wmapT + 512 * 256;                          // (256,256)
  unsigned short* w1T    = wprojT + 256 * 256;                         // (1024,256)
  unsigned short* w2T    = w1T + 1024 * 256;                           // (256,1024)

  k_wprep<<<dim3((512 * 256 + 255) / 256), 256, 0, stream>>>(map_w, wmapT, 256, 512);
  k_wprep<<<dim3((256 * 256 + 255) / 256), 256, 0, stream>>>(proj_w, wprojT, 256, 256);
  k_wprep<<<dim3((1024 * 256 + 255) / 256), 256, 0, stream>>>(w1, w1T, 256, 1024);
  k_wprep<<<dim3((256 * 1024 + 255) / 256), 256, 0, stream>>>(w2, w2T, 1024, 256);

  for (int c = 0; c < nch; ++c) {
    int b0 = c * CH;
    k_xpose<<<dim3(CH * 50, 4), 256, 0, stream>>>(x, b0, xtok);
    k_ln<<<dim3(Mc / 64), 256, 0, stream>>>(xtok, n1w, n1b, xln);
    k_gemm_map<<<dim3(CH * 25, 4), 256, 0, stream>>>(xln, wmapT, map_b, f);
    k_gconv<<<dim3(CH * 64), 256, 0, stream>>>(f, gconv, ycat);
    k_tconv<<<dim3(CH * 64), 256, 0, stream>>>(f, tconv_w, tconv_b, ycat);
    k_attn<<<dim3(40, CH, 4), 256, 0, stream>>>(f, ycat);
    k_gemm_proj<<<dim3(CH * 25, 2), 256, 0, stream>>>(ycat, wprojT, proj_b, xtok);
    k_ln<<<dim3(Mc / 64), 256, 0, stream>>>(xtok, n2w, n2b, xln);
    k_gemm_mlp1<<<dim3(CH * 25, 8), 256, 0, stream>>>(xln, w1T, b1, hmid);
    k_gemm_mlp2<<<dim3(CH * 25, 2), 256, 0, stream>>>(hmid, w2T, b2, xtok, out, b0);
  }
}

// Round 4
// 1003.379 us; speedup vs baseline: 2.7687x; 1.0648x over previous
//
#include <hip/hip_runtime.h>
#include <hip/hip_bf16.h>
#include <math.h>

#define BB  32
#define TVV 3200
#define XB  819200   // 256*3200 floats per batch

typedef __attribute__((ext_vector_type(8))) short s8v;   // 8 x bf16
typedef __attribute__((ext_vector_type(4))) float f4v;   // MFMA acc
typedef unsigned short u16;
typedef unsigned int   u32;

__device__ __forceinline__ u16 f2bf(float f) {
  __hip_bfloat16 h = __float2bfloat16(f);
  union { __hip_bfloat16 h; u16 u; } cv; cv.h = h; return cv.u;
}
__device__ __forceinline__ float bf2f(u16 u) {
  return __uint_as_float(((u32)u) << 16);
}

// async global->LDS, 16B per lane; lds dest = wave-uniform base + lane*16
__device__ __forceinline__ void glds16(const u16* g, u16* l) {
  __builtin_amdgcn_global_load_lds((const __attribute__((address_space(1))) u32*)g,
                                   (__attribute__((address_space(3))) u32*)l, 16, 0, 0);
}

// ---------------- m97-style MFMA core: C(128x128) = A(M,K) x B(N,K)^T
// LDS tiles 128x32 bf16, lane-order (row r at sX + r*32 elems, no pad).
template<int K>
__device__ __forceinline__ void gemm_core(const u16* __restrict__ A, const u16* __restrict__ B,
                                          int m0, int n0, u16* sA, u16* sB, f4v (&acc)[4][4]) {
  const int tid = threadIdx.x, lane = tid & 63, wave = tid >> 6;
  const int wr = wave >> 1, wc = wave & 1;
  const int q = lane >> 4, l15 = lane & 15;
  const int srow = lane >> 2;               // 0..15
  const int skq  = (lane & 3) << 3;         // 0,8,16,24 elems
  const u16* gA = A + (size_t)(m0 + wave * 32 + srow) * K + skq;
  const u16* gB = B + (size_t)(n0 + wave * 32 + srow) * K + skq;
  u16* lA = sA + wave * 1024;               // rows 32w..  (row*32 elems)
  u16* lB = sB + wave * 1024;
  for (int k0 = 0; k0 < K; k0 += 32) {
    glds16(gA + k0,                 lA);
    glds16(gA + k0 + (size_t)16 * K, lA + 512);
    glds16(gB + k0,                 lB);
    glds16(gB + k0 + (size_t)16 * K, lB + 512);
    __syncthreads();
    s8v af[4], bfr[4];
#pragma unroll
    for (int i = 0; i < 4; ++i) {
      af[i]  = *(const s8v*)(sA + (wr * 64 + i * 16 + l15) * 32 + q * 8);
      bfr[i] = *(const s8v*)(sB + (wc * 64 + i * 16 + l15) * 32 + q * 8);
    }
#pragma unroll
    for (int mi = 0; mi < 4; ++mi)
#pragma unroll
      for (int ni = 0; ni < 4; ++ni)
        acc[mi][ni] = __builtin_amdgcn_mfma_f32_16x16x32_bf16(af[mi], bfr[ni], acc[mi][ni], 0, 0, 0);
    __syncthreads();
  }
}

// ---------------- weight prep: src fp32 (K,N) -> dst bf16 (N,K)
__global__ __launch_bounds__(256)
void k_wprep(const float* __restrict__ src, u16* __restrict__ dst, int K, int N) {
  int idx = blockIdx.x * 256 + threadIdx.x;
  if (idx >= N * K) return;
  int n = idx / K, k = idx - n * K;
  dst[idx] = f2bf(src[(size_t)k * N + n]);
}

// ---------------- fused transpose + LN1: x (B,C,T,V) -> xtok fp32 (Mc,256) + xln bf16 (Mc,256)
// one block = 32 tokens x 256 channels
__global__ __launch_bounds__(256)
void k_lnx(const float* __restrict__ x, int b0, const float* __restrict__ w,
           const float* __restrict__ bias, float* __restrict__ xtok, u16* __restrict__ xln) {
  __shared__ float sx[32][264];        // [tok][ch], pad to 264
  __shared__ float srs_[32][33], srq_[32][33];
  __shared__ float smu[32], sst[32];
  int m0 = blockIdx.x * 32;
  int b = b0 + m0 / TVV, tv0 = m0 % TVV;
  int tid = threadIdx.x;
  int qd = tid & 7, c = tid >> 3;      // qd: float4-slot (token quad), c: 0..31
  const float* xb = x + (size_t)b * XB + tv0;
  float wreg = w[tid], breg = bias[tid];
  float s[4] = {0.f, 0.f, 0.f, 0.f}, ss[4] = {0.f, 0.f, 0.f, 0.f};
#pragma unroll
  for (int k = 0; k < 8; ++k) {
    int cc = k * 32 + c;
    float4 vv = *(const float4*)(xb + (size_t)cc * TVV + qd * 4);
    sx[qd * 4 + 0][cc] = vv.x; sx[qd * 4 + 1][cc] = vv.y;
    sx[qd * 4 + 2][cc] = vv.z; sx[qd * 4 + 3][cc] = vv.w;
    s[0] += vv.x; s[1] += vv.y; s[2] += vv.z; s[3] += vv.w;
    ss[0] += vv.x * vv.x; ss[1] += vv.y * vv.y; ss[2] += vv.z * vv.z; ss[3] += vv.w * vv.w;
  }
#pragma unroll
  for (int i = 0; i < 4; ++i) { srs_[qd * 4 + i][c] = s[i]; srq_[qd * 4 + i][c] = ss[i]; }
  __syncthreads();
  if (tid < 32) {
    float t1 = 0.f, t2 = 0.f;
#pragma unroll
    for (int j = 0; j < 32; ++j) { t1 += srs_[tid][j]; t2 += srq_[tid][j]; }
    float mu = t1 * (1.f / 256.f);
    smu[tid] = mu;
    sst[tid] = rsqrtf(t2 * (1.f / 256.f) - mu * mu + 1e-5f);
  }
  __syncthreads();
  for (int tok = 0; tok < 32; ++tok) {
    float val = sx[tok][tid];
    float mu = smu[tok], rs = sst[tok];
    size_t m = (size_t)(m0 + tok) * 256 + tid;
    xtok[m] = val;
    xln[m]  = f2bf((val - mu) * rs * wreg + breg);
  }
}

// ---------------- LayerNorm (over 256) fp32 token-major src -> bf16 dst
__global__ __launch_bounds__(256)
void k_ln(const float* __restrict__ src, const float* __restrict__ w, const float* __restrict__ b,
          u16* __restrict__ dst) {
  int tid = threadIdx.x;
  int tk = tid >> 2, p = tid & 3;
  size_t m = (size_t)blockIdx.x * 64 + tk;
  const float4* row = (const float4*)(src + m * 256 + p * 64);
  float4 r[16];
  float s = 0.f, ss = 0.f;
#pragma unroll
  for (int j = 0; j < 16; ++j) {
    r[j] = row[j];
    s  += r[j].x + r[j].y + r[j].z + r[j].w;
    ss += r[j].x*r[j].x + r[j].y*r[j].y + r[j].z*r[j].z + r[j].w*r[j].w;
  }
  __shared__ float sb1[256], sb2[256];
  sb1[tid] = s; sb2[tid] = ss;
  __syncthreads();
  int base = tk << 2;
  s  = sb1[base] + sb1[base+1] + sb1[base+2] + sb1[base+3];
  ss = sb2[base] + sb2[base+1] + sb2[base+2] + sb2[base+3];
  float mu = s * (1.f / 256.f);
  float rstd = rsqrtf(ss * (1.f / 256.f) - mu * mu + 1e-5f);
  ushort4* drow = (ushort4*)(dst + m * 256 + p * 64);
#pragma unroll
  for (int j = 0; j < 16; ++j) {
    int c = p * 64 + j * 4;
    ushort4 o;
    o.x = f2bf((r[j].x - mu) * rstd * w[c]     + b[c]);
    o.y = f2bf((r[j].y - mu) * rstd * w[c + 1] + b[c + 1]);
    o.z = f2bf((r[j].z - mu) * rstd * w[c + 2] + b[c + 2]);
    o.w = f2bf((r[j].w - mu) * rstd * w[c + 3] + b[c + 3]);
    drow[j] = o;
  }
}

// ---------------- map GEMM: xln(Mc,256) x wmapT(512,256) + bias -> f bf16 (Mc,512)
__global__ __launch_bounds__(256)
void k_gemm_map(const u16* __restrict__ xln, const u16* __restrict__ wT,
                const float* __restrict__ bias, u16* __restrict__ f) {
  __shared__ __align__(16) u16 sm[8192];
  int m0 = blockIdx.x * 128, n0 = blockIdx.y * 128;
  f4v acc[4][4];
#pragma unroll
  for (int i = 0; i < 4; ++i)
#pragma unroll
    for (int j = 0; j < 4; ++j) acc[i][j] = (f4v){0.f, 0.f, 0.f, 0.f};
  gemm_core<256>(xln, wT, m0, n0, sm, sm + 4096, acc);
  const int tid = threadIdx.x, lane = tid & 63, wave = tid >> 6;
  const int wr = wave >> 1, wc = wave & 1, q = lane >> 4, l15 = lane & 15;
#pragma unroll
  for (int ni = 0; ni < 4; ++ni) {
    int n = n0 + wc * 64 + ni * 16 + l15;
    float bz = bias[n];
#pragma unroll
    for (int mi = 0; mi < 4; ++mi) {
      int m = m0 + wr * 64 + mi * 16 + q * 4;
#pragma unroll
      for (int rr = 0; rr < 4; ++rr)
        f[(size_t)(m + rr) * 512 + n] = f2bf(acc[mi][ni][rr] + bz);
    }
  }
}

// ---------------- proj GEMM: ycat(Mc,256) x wprojT(256,256) + bias + skip (in-place xtok)
__global__ __launch_bounds__(256)
void k_gemm_proj(const u16* __restrict__ ycat, const u16* __restrict__ wT,
                 const float* __restrict__ bias, float* __restrict__ out1) {
  __shared__ __align__(16) u16 sm[8192];
  int m0 = blockIdx.x * 128, n0 = blockIdx.y * 128;
  f4v acc[4][4];
#pragma unroll
  for (int i = 0; i < 4; ++i)
#pragma unroll
    for (int j = 0; j < 4; ++j) acc[i][j] = (f4v){0.f, 0.f, 0.f, 0.f};
  gemm_core<256>(ycat, wT, m0, n0, sm, sm + 4096, acc);
  const int tid = threadIdx.x, lane = tid & 63, wave = tid >> 6;
  const int wr = wave >> 1, wc = wave & 1, q = lane >> 4, l15 = lane & 15;
#pragma unroll
  for (int ni = 0; ni < 4; ++ni) {
    int n = n0 + wc * 64 + ni * 16 + l15;
    float bz = bias[n];
#pragma unroll
    for (int mi = 0; mi < 4; ++mi) {
      int m = m0 + wr * 64 + mi * 16 + q * 4;
#pragma unroll
      for (int rr = 0; rr < 4; ++rr) {
        size_t idx = (size_t)(m + rr) * 256 + n;
        out1[idx] = out1[idx] + acc[mi][ni][rr] + bz;
      }
    }
  }
}

// ---------------- mlp1 GEMM: xln2(Mc,256) x w1T(1024,256) + bias -> GELU -> hmid bf16 (Mc,1024)
__global__ __launch_bounds__(256)
void k_gemm_mlp1(const u16* __restrict__ xln2, const u16* __restrict__ wT,
                 const float* __restrict__ bias, u16* __restrict__ hmid) {
  __shared__ __align__(16) u16 sm[8192];
  int m0 = blockIdx.x * 128, n0 = blockIdx.y * 128;
  f4v acc[4][4];
#pragma unroll
  for (int i = 0; i < 4; ++i)
#pragma unroll
    for (int j = 0; j < 4; ++j) acc[i][j] = (f4v){0.f, 0.f, 0.f, 0.f};
  gemm_core<256>(xln2, wT, m0, n0, sm, sm + 4096, acc);
  const int tid = threadIdx.x, lane = tid & 63, wave = tid >> 6;
  const int wr = wave >> 1, wc = wave & 1, q = lane >> 4, l15 = lane & 15;
#pragma unroll
  for (int ni = 0; ni < 4; ++ni) {
    int n = n0 + wc * 64 + ni * 16 + l15;
    float bz = bias[n];
#pragma unroll
    for (int mi = 0; mi < 4; ++mi) {
      int m = m0 + wr * 64 + mi * 16 + q * 4;
#pragma unroll
      for (int rr = 0; rr < 4; ++rr) {
        float h = acc[mi][ni][rr] + bz;
        float g = 0.5f * h * (1.f + erff(h * 0.70710678118654752f));
        hmid[(size_t)(m + rr) * 1024 + n] = f2bf(g);
      }
    }
  }
}

// ---------------- mlp2 GEMM: hmid(Mc,1024) x w2T(256,1024) + bias + out1 -> d_out (B,C,T,V)
__global__ __launch_bounds__(256)
void k_gemm_mlp2(const u16* __restrict__ hmid, const u16* __restrict__ wT,
                 const float* __restrict__ bias, const float* __restrict__ out1,
                 float* __restrict__ out, int b0) {
  __shared__ __align__(16) u16 sm[10240];   // 20480 B: 16 KB tiles + transpose scratch
  int m0 = blockIdx.x * 128, n0 = blockIdx.y * 128;
  f4v acc[4][4];
#pragma unroll
  for (int i = 0; i < 4; ++i)
#pragma unroll
    for (int j = 0; j < 4; ++j) acc[i][j] = (f4v){0.f, 0.f, 0.f, 0.f};
  gemm_core<1024>(hmid, wT, m0, n0, sm, sm + 4096, acc);
  const int tid = threadIdx.x, lane = tid & 63, wave = tid >> 6;
  const int wr = wave >> 1, wc = wave & 1, q = lane >> 4, l15 = lane & 15;
  float* twv = (float*)sm + wave * 16 * 65;   // 4 waves * 1040 floats = 16640 B
  int mbase = m0 + wr * 64;
  int bglob = b0 + mbase / TVV;
  int tvb = mbase % TVV;
  for (int ni = 0; ni < 4; ++ni) {
    int n = n0 + wc * 64 + ni * 16 + l15;
    float bz = bias[n];
#pragma unroll
    for (int mi = 0; mi < 4; ++mi) {
      int ml = mi * 16 + q * 4;
#pragma unroll
      for (int rr = 0; rr < 4; ++rr) {
        int m = mbase + ml + rr;
        twv[l15 * 65 + ml + rr] = acc[mi][ni][rr] + bz + out1[(size_t)m * 256 + n];
      }
    }
    __syncthreads();
#pragma unroll
    for (int np = 0; np < 16; ++np) {
      int n2 = n0 + wc * 64 + ni * 16 + np;
      out[((size_t)bglob * 256 + n2) * TVV + tvb + lane] = twv[np * 65 + lane];
    }
    __syncthreads();
  }
}

// ---------------- grouped graph conv over V: f ch 0..63 -> ycat ch 0..63
__global__ __launch_bounds__(256)
void k_gconv(const u16* __restrict__ f, const float* __restrict__ gw,
             u16* __restrict__ ycat) {
  __shared__ float sf[50][64];
  int bc = blockIdx.x >> 6, t = blockIdx.x & 63;
  int tid = threadIdx.x;
  size_t tok0 = (size_t)bc * TVV + t * 50;
  for (int idx = tid; idx < 3200; idx += 256) {
    int u = idx >> 6, oc = idx & 63;
    sf[u][oc] = bf2f(f[(tok0 + u) * 512 + oc]);
  }
  __syncthreads();
  for (int idx = tid; idx < 3200; idx += 256) {
    int v = idx >> 6, oc = idx & 63;
    const float* gr = gw + ((size_t)(oc >> 3) * 50 + v) * 50;
    float s = 0.f;
#pragma unroll 10
    for (int u = 0; u < 50; ++u) s += sf[u][oc] * gr[u];
    ycat[(tok0 + v) * 256 + oc] = f2bf(s);
  }
}

// ---------------- grouped temporal conv k=7 pad3: f ch 64..127 -> ycat ch 64..127
__global__ __launch_bounds__(256)
void k_tconv(const u16* __restrict__ f, const float* __restrict__ tw,
             const float* __restrict__ tb, u16* __restrict__ ycat) {
  __shared__ float sw[64 * 57];
  int bc = blockIdx.x >> 6, t = blockIdx.x & 63;
  int tid = threadIdx.x;
  for (int idx = tid; idx < 64 * 56; idx += 256) {
    int oc = idx / 56, k = idx - oc * 56;
    sw[oc * 57 + k] = tw[idx];
  }
  __syncthreads();
  size_t base = (size_t)bc * TVV;
  for (int idx = tid; idx < 3200; idx += 256) {
    int v = idx >> 6, oc = idx & 63;
    int g = oc >> 3;
    float s = tb[oc];
#pragma unroll
    for (int kt = 0; kt < 7; ++kt) {
      int ts = t + kt - 3;
      if (ts < 0 || ts >= 64) continue;
      s8v fv = *(const s8v*)(f + (base + ts * 50 + v) * 512 + 64 + g * 8);
      const float* wr_ = sw + oc * 57 + kt;
#pragma unroll
      for (int ic = 0; ic < 8; ++ic) s += bf2f((u16)fv[ic]) * wr_[ic * 7];
    }
    ycat[(base + t * 50 + v) * 256 + 64 + oc] = f2bf(s);
  }
}

// ---------------- windowed hyperbolic linear attention -> ycat ch 128..255
__global__ __launch_bounds__(256)
void k_attn(const u16* __restrict__ f, u16* __restrict__ ycat) {
  int mode = blockIdx.z, bc = blockIdx.y;
  int wt = blockIdx.x / 5, wv = blockIdx.x % 5;
  __shared__ float parts[80][97];
  __shared__ float kvb[256];
  __shared__ float obuf[80][33];
  __shared__ float scl[80];
  int tid = threadIdx.x;
  size_t base = (size_t)bc * TVV;
  int ch0 = 128 + mode * 96;
  for (int idx = tid; idx < 80 * 96; idx += 256) {
    int n = idx / 96, ch = idx - n * 96;
    int lt = n / 10, lv = n - lt * 10;
    int t = (mode < 2) ? (wt * 8 + lt) : (lt * 8 + wt);
    int v = ((mode & 1) == 0) ? (wv * 10 + lv) : (lv * 5 + wv);
    parts[n][ch] = bf2f(f[(base + t * 50 + v) * 512 + ch0 + ch]);
  }
  __syncthreads();
  if (tid < 80) {
    float s = 0.f;
    for (int ch = 0; ch < 96; ++ch) { float val = parts[tid][ch]; s += val * val; }
    float nrm = fmaxf(sqrtf(s), 1e-10f);
    float sc = tanhf(nrm) / nrm;
    for (int ch = 0; ch < 96; ++ch) parts[tid][ch] *= sc;
  }
  __syncthreads();
  {
    int h = tid >> 6, dd = (tid >> 3) & 7, e = tid & 7;
    float s = 0.f;
    for (int n = 0; n < 80; ++n)
      s += parts[n][32 + h * 8 + dd] * parts[n][64 + h * 8 + e];
    kvb[tid] = s;
  }
  __syncthreads();
  if (tid < 32) {
    int h = tid >> 3, dd = tid & 7;
    float* r = &kvb[h * 64 + dd * 8];
    float mx = r[0];
    for (int e = 1; e < 8; ++e) mx = fmaxf(mx, r[e]);
    float ex[8]; float sm2 = 0.f;
    for (int e = 0; e < 8; ++e) { ex[e] = expf(r[e] - mx); sm2 += ex[e]; }
    float inv = 1.f / sm2;
    for (int e = 0; e < 8; ++e) r[e] = ex[e] * inv;
  }
  __syncthreads();
  for (int idx = tid; idx < 80 * 32; idx += 256) {
    int n = idx >> 5, cc = idx & 31;
    int h = cc >> 3, m_ = cc & 7;
    float s = 0.f;
#pragma unroll
    for (int i = 0; i < 8; ++i)
      s += parts[n][h * 8 + i] * kvb[h * 64 + m_ * 8 + i];
    obuf[n][cc] = s * 0.5f;
  }
  __syncthreads();
  if (tid < 80) {
    float s = 0.f;
    for (int cc = 0; cc < 32; ++cc) { float val = obuf[tid][cc]; s += val * val; }
    float nn = sqrtf(s);
    nn = fminf(fmaxf(nn, 1e-10f), 1.f - 1e-5f);
    scl[tid] = -atanhf(nn) / nn;
  }
  __syncthreads();
  for (int idx = tid; idx < 80 * 32; idx += 256) {
    int n = idx >> 5, cc = idx & 31;
    int lt = n / 10, lv = n - lt * 10;
    int t = (mode < 2) ? (wt * 8 + lt) : (lt * 8 + wt);
    int v = ((mode & 1) == 0) ? (wv * 10 + lv) : (lv * 5 + wv);
    ycat[(base + t * 50 + v) * 256 + 128 + mode * 32 + cc] = f2bf(obuf[n][cc] * scl[n]);
  }
}

extern "C" void kernel_launch(void* const* d_in, const int* in_sizes, int n_in,
                              void* d_out, int out_size, void* d_ws, size_t ws_size,
                              hipStream_t stream) {
  const float* x       = (const float*)d_in[0];
  const float* n1w     = (const float*)d_in[1];
  const float* n1b     = (const float*)d_in[2];
  const float* map_w   = (const float*)d_in[3];
  const float* map_b   = (const float*)d_in[4];
  const float* gconv   = (const float*)d_in[5];
  const float* tconv_w = (const float*)d_in[6];
  const float* tconv_b = (const float*)d_in[7];
  const float* proj_w  = (const float*)d_in[8];
  const float* proj_b  = (const float*)d_in[9];
  const float* n2w     = (const float*)d_in[10];
  const float* n2b     = (const float*)d_in[11];
  const float* w1      = (const float*)d_in[12];
  const float* b1      = (const float*)d_in[13];
  const float* w2      = (const float*)d_in[14];
  const float* b2      = (const float*)d_in[15];
  float* out = (float*)d_out;

  // per-token ws: xtok/out1 fp32 (1024 B) | region2 2048 B: f bf16 (Mc,512) overlaid
  // with hmid bf16 (Mc,1024) | xln bf16 (512 B) | ycat bf16 (512 B) = 4096 B/token
  const size_t WB = (size_t)(512 * 256 + 256 * 256 + 1024 * 256 + 256 * 1024) * 2;
  int CH = 32;
  while (CH > 1 && (size_t)CH * TVV * 4096 + WB > ws_size) CH >>= 1;
  if ((size_t)CH * TVV * 4096 + WB > ws_size) return;
  const int Mc = CH * TVV;
  const int nch = BB / CH;

  char* ws = (char*)d_ws;
  float* xtok   = (float*)ws;                                // (Mc,256) fp32; becomes out1
  u16* f        = (u16*)(ws + (size_t)Mc * 1024);            // (Mc,512) bf16
  u16* hmid     = f;                                         // (Mc,1024) bf16 overlay
  u16* xln      = (u16*)(ws + (size_t)Mc * 3072);            // (Mc,256) bf16
  u16* ycat     = (u16*)(ws + (size_t)Mc * 3584);            // (Mc,256) bf16
  u16* wmapT    = (u16*)(ws + (size_t)Mc * 4096);            // (512,256)
  u16* wprojT   = wmapT + 512 * 256;                         // (256,256)
  u16* w1T      = wprojT + 256 * 256;                        // (1024,256)
  u16* w2T      = w1T + 1024 * 256;                          // (256,1024)

  k_wprep<<<dim3(512), 256, 0, stream>>>(map_w, wmapT, 256, 512);
  k_wprep<<<dim3(256), 256, 0, stream>>>(proj_w, wprojT, 256, 256);
  k_wprep<<<dim3(1024), 256, 0, stream>>>(w1, w1T, 256, 1024);
  k_wprep<<<dim3(1024), 256, 0, stream>>>(w2, w2T, 1024, 256);

  for (int c = 0; c < nch; ++c) {
    int b0 = c * CH;
    k_lnx<<<dim3(Mc / 32), 256, 0, stream>>>(x, b0, n1w, n1b, xtok, xln);
    k_gemm_map<<<dim3(Mc / 128, 4), 256, 0, stream>>>(xln, wmapT, map_b, f);
    k_gconv<<<dim3(CH * 64), 256, 0, stream>>>(f, gconv, ycat);
    k_tconv<<<dim3(CH * 64), 256, 0, stream>>>(f, tconv_w, tconv_b, ycat);
    k_attn<<<dim3(40, CH, 4), 256, 0, stream>>>(f, ycat);
    k_gemm_proj<<<dim3(Mc / 128, 2), 256, 0, stream>>>(ycat, wprojT, proj_b, xtok);
    k_ln<<<dim3(Mc / 64), 256, 0, stream>>>(xtok, n2w, n2b, xln);
    k_gemm_mlp1<<<dim3(Mc / 128, 8), 256, 0, stream>>>(xln, w1T, b1, hmid);
    k_gemm_mlp2<<<dim3(Mc / 128, 2), 256, 0, stream>>>(hmid, w2T, b2, xtok, out, b0);
  }
}